// Round 1
// 520.339 us; speedup vs baseline: 1.6363x; 1.6363x over previous
//
#include <hip/hip_runtime.h>
#include <hip/hip_bf16.h>

#define DIMC 128
#define HD   32
#define NTOK 49
#define SSTR 136   // ushort stride for [64][128+pad] LDS tiles
#define VSTR 72    // ushort stride for 64-wide tiles (Vt, P-tile); 144B rows keep 16B align

// LDS layout (bytes):
//  region A @0      : sQ [64][136] bf16 = 17408
//                     later: per-wave P tiles (4 x [16][72] ushort = 9216 B total)
//                     later: X' [64][136] (PV output)
//  region B @17408  : sK [64][136] = 17408
//  region C @34816  : sVt [128][72] = 18432  (V^T: rows=features, cols=tokens)
#define OFF_K      17408
#define OFF_VT     34816
#define SMEM_BYTES 53248   // 53,248 * 3 = 159,744 <= 163,840 -> 3 blocks/CU

// workspace layout (bytes). total ~4.13 MB
#define WS_WFRAG   1024                     // ushort[4 mats][8 ntile][4 k][64 lane][8] = 131072 B
#define WS_ADDB    (1024 + 131072)          // float [64 wi][4 h][16 rtct][64 lane][4 r] = 4194304 B
#define WS_BIAS    (1024 + 131072 + 4194304) // float[4][128] = 2048 B

using bf16x8 = __attribute__((ext_vector_type(8))) __bf16;
using u16x8  = __attribute__((ext_vector_type(8))) ushort;
using f32x4  = __attribute__((ext_vector_type(4))) float;

static __device__ __forceinline__ ushort f2b(float f) {
  __hip_bfloat16 h = __float2bfloat16(f);
  return __builtin_bit_cast(ushort, h);
}
static __device__ __forceinline__ float b2f(ushort u) {
  __hip_bfloat16 h = __builtin_bit_cast(__hip_bfloat16, u);
  return __bfloat162float(h);
}
// NaN-scrubbing clamp
static __device__ __forceinline__ float scrub(float v, float lim) {
  return fminf(fmaxf(v, -lim), lim);
}
static __device__ __forceinline__ float ldany(const void* p, int i, int isbf) {
  return isbf ? b2f(((const ushort*)p)[i]) : ((const float*)p)[i];
}

// Detect whether "float" inputs were delivered as bf16 (ushort) or fp32.
__global__ void detect_dtype_kernel(const ushort* __restrict__ q, int* __restrict__ flag) {
  if (threadIdx.x == 0 && blockIdx.x == 0) {
    int c = 0;
    for (int i = 0; i < 256; ++i) {
      int e = (q[i] >> 7) & 0xFF;
      c += (e >= 110 && e <= 133) ? 1 : 0;
    }
    *flag = (c >= 200) ? 1 : 0;
  }
}

// One-time prep: weights -> bf16 fragment-major; biases -> f32; (rel_bias + mask) -> f32
// table in exact MFMA C/D accumulator layout.
__global__ __launch_bounds__(256) void prep_kernel(
    const void* __restrict__ Wq, const void* __restrict__ Wk,
    const void* __restrict__ Wv, const void* __restrict__ Wp,
    const void* __restrict__ bq, const void* __restrict__ bk,
    const void* __restrict__ bv, const void* __restrict__ bp,
    const void* __restrict__ btab, const void* __restrict__ gmask,
    const int* __restrict__ relidx,
    ushort* __restrict__ wfrag, float* __restrict__ addb, float* __restrict__ biasf,
    const int* __restrict__ flag)
{
  const int isbf = *flag;
  const int gtid = blockIdx.x * 256 + threadIdx.x;
  const int gstr = gridDim.x * 256;
  const void* Ws[4] = {Wq, Wk, Wv, Wp};
  const void* bs[4] = {bq, bk, bv, bp};

  // weight fragments: element (mat, nt, k, lane, j) = W[mat][nt*16+(lane&15)][k*32+(lane>>4)*8+j]
  for (int i = gtid; i < 4 * 16384; i += gstr) {
    int mat = i >> 14;
    int nt  = (i >> 11) & 7;
    int k   = (i >> 9) & 3;
    int ln  = (i >> 3) & 63;
    int j   = i & 7;
    int row = nt * 16 + (ln & 15);
    int col = k * 32 + (ln >> 4) * 8 + j;
    wfrag[i] = f2b(ldany(Ws[mat], row * DIMC + col, isbf));
  }
  for (int i = gtid; i < 512; i += gstr)
    biasf[i] = ldany(bs[i >> 7], i & 127, isbf);

  // addb: i = (((wi*4+h)*16 + rt*4+ct)*64 + lane)*4 + r
  for (int i = gtid; i < 64 * 4 * 16 * 64 * 4; i += gstr) {
    int r  = i & 3;
    int ln = (i >> 2) & 63;
    int rc = (i >> 8) & 15;
    int h  = (i >> 12) & 3;
    int wi = i >> 14;
    int rt = rc >> 2, ct = rc & 3;
    int n = rt * 16 + (ln >> 4) * 4 + r;
    int m = ct * 16 + (ln & 15);
    float v;
    if (n >= NTOK || m >= NTOK) {
      v = -30000.f;  // scores there are exactly 0 (zeroed Q/K rows), so masked hard
    } else {
      int ri = relidx[n * NTOK + m];
      v = ldany(btab, ri * 4 + h, isbf) + ldany(gmask, (wi * NTOK + n) * NTOK + m, isbf);
    }
    addb[i] = v;
  }
}

__global__ __launch_bounds__(256, 3) void swin_attn_kernel(
    const void* __restrict__ gq, const void* __restrict__ gk, const void* __restrict__ gv,
    const ushort* __restrict__ wfrag, const float* __restrict__ addb,
    const float* __restrict__ biasf,
    void* __restrict__ goutv, const int* __restrict__ flag)
{
  __shared__ __align__(16) char smem[SMEM_BYTES];
  ushort* sQ  = (ushort*)smem;
  ushort* sK  = (ushort*)(smem + OFF_K);
  ushort* sVt = (ushort*)(smem + OFF_VT);

  const int b    = blockIdx.x;
  const int tid  = threadIdx.x;
  const int wave = tid >> 6;
  const int lane = tid & 63;
  const int quad = lane >> 4;
  const int l16  = lane & 15;
  const int wi   = b & 63;
  const int isbf = *flag;
  const int h    = wave, koff = h * HD;
  const int n0a  = wave * 32, n0b = n0a + 16;

  // A-fragment of X loaded straight from global (rows >= NTOK -> 0)
  auto ldxfrag = [&](const void* src, int row, int col) -> bf16x8 {
    u16x8 u = {0, 0, 0, 0, 0, 0, 0, 0};
    if (row < NTOK) {
      if (isbf) {
        const ushort* s = (const ushort*)src + (size_t)b * NTOK * DIMC + row * DIMC + col;
        u = *(const u16x8*)s;
      } else {
        const float* s = (const float*)src + (size_t)b * NTOK * DIMC + row * DIMC + col;
        float4 f0 = *(const float4*)s;
        float4 f1 = *(const float4*)(s + 4);
        u[0] = f2b(f0.x); u[1] = f2b(f0.y); u[2] = f2b(f0.z); u[3] = f2b(f0.w);
        u[4] = f2b(f1.x); u[5] = f2b(f1.y); u[6] = f2b(f1.z); u[7] = f2b(f1.w);
      }
    }
    return __builtin_bit_cast(bf16x8, u);
  };

  // Projection: out[t][i] = sum_c X[t][c] * W[i][c] + bias[i]
  // wave `w` computes output features n0a..n0a+31 (= its own head's slice).
  // p: 0 -> sQ [token][feat], 1 -> sK [token][feat], 2 -> sVt [feat][token]
  auto proj = [&](const void* src, int mat, int p) {
    const ushort* wb = wfrag + mat * 16384;
    bf16x8 bfr[2][4];
#pragma unroll
    for (int k = 0; k < 4; ++k) {
      bfr[0][k] = *(const bf16x8*)&wb[(((n0a >> 4) * 4) + k) * 512 + lane * 8];
      bfr[1][k] = *(const bf16x8*)&wb[(((n0b >> 4) * 4) + k) * 512 + lane * 8];
    }
    const float b0 = biasf[mat * 128 + n0a + l16];
    const float b1 = biasf[mat * 128 + n0b + l16];
#pragma unroll
    for (int mt = 0; mt < 4; ++mt) {
      bf16x8 af[4];
#pragma unroll
      for (int k = 0; k < 4; ++k)
        af[k] = ldxfrag(src, mt * 16 + l16, k * 32 + quad * 8);
      f32x4 a0 = {0.f, 0.f, 0.f, 0.f}, a1 = {0.f, 0.f, 0.f, 0.f};
#pragma unroll
      for (int k = 0; k < 4; ++k) {
        a0 = __builtin_amdgcn_mfma_f32_16x16x32_bf16(af[k], bfr[0][k], a0, 0, 0, 0);
        a1 = __builtin_amdgcn_mfma_f32_16x16x32_bf16(af[k], bfr[1][k], a1, 0, 0, 0);
      }
      if (p == 2) {
        // V^T: row = feature, col = token (tokens >= NTOK get bv: harmless, P=0 there)
        ushort4 pk;
        pk.x = f2b(scrub(a0[0] + b0, 30000.f)); pk.y = f2b(scrub(a0[1] + b0, 30000.f));
        pk.z = f2b(scrub(a0[2] + b0, 30000.f)); pk.w = f2b(scrub(a0[3] + b0, 30000.f));
        *(ushort4*)&sVt[(n0a + l16) * VSTR + mt * 16 + quad * 4] = pk;
        pk.x = f2b(scrub(a1[0] + b1, 30000.f)); pk.y = f2b(scrub(a1[1] + b1, 30000.f));
        pk.z = f2b(scrub(a1[2] + b1, 30000.f)); pk.w = f2b(scrub(a1[3] + b1, 30000.f));
        *(ushort4*)&sVt[(n0b + l16) * VSTR + mt * 16 + quad * 4] = pk;
      } else {
        ushort* dst = p ? sK : sQ;
#pragma unroll
        for (int r = 0; r < 4; ++r) {
          int row = mt * 16 + quad * 4 + r;
          // tokens >= NTOK: suppress bias so Q/K rows are exactly 0 -> masked scores exactly 0
          float bb0 = (row < NTOK) ? b0 : 0.f;
          float bb1 = (row < NTOK) ? b1 : 0.f;
          dst[row * SSTR + n0a + l16] = f2b(scrub(a0[r] + bb0, 30000.f));
          dst[row * SSTR + n0b + l16] = f2b(scrub(a1[r] + bb1, 30000.f));
        }
      }
    }
  };

  // ---- QKV projections (all LDS writes/reads here are wave-private: no barriers) ----
  proj(gq, 0, 0);
  proj(gk, 1, 1);
  proj(gv, 2, 2);

  // ---- scores: wave h owns head h; qa/kb read own wave's columns ----
  bf16x8 qa[4], kb[4];
#pragma unroll
  for (int t = 0; t < 4; ++t) {
    qa[t] = *(const bf16x8*)&sQ[(t * 16 + l16) * SSTR + koff + quad * 8];
    kb[t] = *(const bf16x8*)&sK[(t * 16 + l16) * SSTR + koff + quad * 8];
  }
  __syncthreads();  // B1: everyone holds qa/kb before P scratch clobbers region A

  f32x4 s[4][4];
#pragma unroll
  for (int rt = 0; rt < 4; ++rt)
#pragma unroll
    for (int ct = 0; ct < 4; ++ct) {
      f32x4 z = {0.f, 0.f, 0.f, 0.f};
      s[rt][ct] = __builtin_amdgcn_mfma_f32_16x16x32_bf16(qa[rt], kb[ct], z, 0, 0, 0);
    }

  // ---- scale + precomputed (rel_bias + mask) in C/D layout, then register softmax ----
  const float scale = 0.17677669529663687f;  // 1/sqrt(32)
  const float* ab = addb + (size_t)(wi * 4 + h) * 16 * 256 + lane * 4;
#pragma unroll
  for (int rt = 0; rt < 4; ++rt) {
#pragma unroll
    for (int ct = 0; ct < 4; ++ct) {
      f32x4 a4 = *(const f32x4*)(ab + (rt * 4 + ct) * 256);
#pragma unroll
      for (int r = 0; r < 4; ++r)
        s[rt][ct][r] = scrub(s[rt][ct][r] * scale + a4[r], 30000.f);
    }
#pragma unroll
    for (int r = 0; r < 4; ++r) {
      float m0 = fmaxf(fmaxf(s[rt][0][r], s[rt][1][r]), fmaxf(s[rt][2][r], s[rt][3][r]));
      m0 = fmaxf(m0, __shfl_xor(m0, 1));
      m0 = fmaxf(m0, __shfl_xor(m0, 2));
      m0 = fmaxf(m0, __shfl_xor(m0, 4));
      m0 = fmaxf(m0, __shfl_xor(m0, 8));
      float t0 = 0.f;
#pragma unroll
      for (int ct = 0; ct < 4; ++ct) {
        float e = __expf(s[rt][ct][r] - m0);
        s[rt][ct][r] = e;
        t0 += e;
      }
      t0 += __shfl_xor(t0, 1);
      t0 += __shfl_xor(t0, 2);
      t0 += __shfl_xor(t0, 4);
      t0 += __shfl_xor(t0, 8);
      float inv = 1.0f / fmaxf(t0, 1e-20f);
#pragma unroll
      for (int ct = 0; ct < 4; ++ct) s[rt][ct][r] *= inv;
    }
  }

  // ---- P layout round-trip, one 16-row tile at a time (wave-private [16][72] scratch) ----
  ushort* sP = sQ + wave * 1152;  // 2304 B per wave, 4 waves = 9216 B inside region A
  bf16x8 pa[4][2];
#pragma unroll
  for (int rt = 0; rt < 4; ++rt) {
#pragma unroll
    for (int ct = 0; ct < 4; ++ct)
#pragma unroll
      for (int r = 0; r < 4; ++r)
        sP[(quad * 4 + r) * VSTR + ct * 16 + l16] = f2b(s[rt][ct][r]);
    // DS ops from one wave complete in order; compiler inserts lgkmcnt waits
#pragma unroll
    for (int ks = 0; ks < 2; ++ks)
      pa[rt][ks] = *(const bf16x8*)&sP[l16 * VSTR + ks * 32 + quad * 8];
  }

  // ---- PV: vb reads own wave's Vt rows (wave-private) ----
  bf16x8 vb[2][2];
#pragma unroll
  for (int ct = 0; ct < 2; ++ct)
#pragma unroll
    for (int ks = 0; ks < 2; ++ks)
      vb[ct][ks] = *(const bf16x8*)&sVt[(koff + ct * 16 + l16) * VSTR + ks * 32 + quad * 8];
  f32x4 xacc[4][2];
#pragma unroll
  for (int rt = 0; rt < 4; ++rt)
#pragma unroll
    for (int ct = 0; ct < 2; ++ct) {
      f32x4 z = {0.f, 0.f, 0.f, 0.f};
      z = __builtin_amdgcn_mfma_f32_16x16x32_bf16(pa[rt][0], vb[ct][0], z, 0, 0, 0);
      xacc[rt][ct] = __builtin_amdgcn_mfma_f32_16x16x32_bf16(pa[rt][1], vb[ct][1], z, 0, 0, 0);
    }
  __syncthreads();  // B2: all P-scratch reads done before X' overwrites region A

  // ---- X' -> region A as [64][136] ----
  ushort* sXp = sQ;
#pragma unroll
  for (int rt = 0; rt < 4; ++rt)
#pragma unroll
    for (int ct = 0; ct < 2; ++ct)
#pragma unroll
      for (int r = 0; r < 4; ++r) {
        int row = rt * 16 + quad * 4 + r;
        sXp[row * SSTR + koff + ct * 16 + l16] = f2b(scrub(xacc[rt][ct][r], 1e4f));
      }
  __syncthreads();  // B3: out-proj reads all X' columns

  // ---- output projection ----
  {
    const ushort* wb = wfrag + 3 * 16384;
    bf16x8 wf[2][4];
#pragma unroll
    for (int k = 0; k < 4; ++k) {
      wf[0][k] = *(const bf16x8*)&wb[(((n0a >> 4) * 4) + k) * 512 + lane * 8];
      wf[1][k] = *(const bf16x8*)&wb[(((n0b >> 4) * 4) + k) * 512 + lane * 8];
    }
    const float bo0 = biasf[3 * 128 + n0a + l16];
    const float bo1 = biasf[3 * 128 + n0b + l16];
#pragma unroll
    for (int mt = 0; mt < 4; ++mt) {
      bf16x8 af[4];
#pragma unroll
      for (int k = 0; k < 4; ++k)
        af[k] = *(const bf16x8*)&sXp[(mt * 16 + l16) * SSTR + k * 32 + quad * 8];
      f32x4 a0 = {0.f, 0.f, 0.f, 0.f}, a1 = {0.f, 0.f, 0.f, 0.f};
#pragma unroll
      for (int k = 0; k < 4; ++k) {
        a0 = __builtin_amdgcn_mfma_f32_16x16x32_bf16(af[k], wf[0][k], a0, 0, 0, 0);
        a1 = __builtin_amdgcn_mfma_f32_16x16x32_bf16(af[k], wf[1][k], a1, 0, 0, 0);
      }
#pragma unroll
      for (int r = 0; r < 4; ++r) {
        int row = mt * 16 + quad * 4 + r;
        if (row < NTOK) {
          size_t o = (size_t)(b * NTOK + row) * DIMC;
          float v0 = scrub(a0[r] + bo0, 1e4f);
          float v1 = scrub(a1[r] + bo1, 1e4f);
          if (isbf) {
            ((__hip_bfloat16*)goutv)[o + n0a + l16] = __float2bfloat16(v0);
            ((__hip_bfloat16*)goutv)[o + n0b + l16] = __float2bfloat16(v1);
          } else {
            ((float*)goutv)[o + n0a + l16] = v0;
            ((float*)goutv)[o + n0b + l16] = v1;
          }
        }
      }
    }
  }
}

extern "C" void kernel_launch(void* const* d_in, const int* in_sizes, int n_in,
                              void* d_out, int out_size, void* d_ws, size_t ws_size,
                              hipStream_t stream) {
  const int B = in_sizes[0] / (NTOK * DIMC);  // 4096
  int* flag = (int*)d_ws;
  ushort* wfrag = (ushort*)((char*)d_ws + WS_WFRAG);
  float* addb = (float*)((char*)d_ws + WS_ADDB);
  float* biasf = (float*)((char*)d_ws + WS_BIAS);
  detect_dtype_kernel<<<1, 64, 0, stream>>>((const ushort*)d_in[0], flag);
  prep_kernel<<<512, 256, 0, stream>>>(
      d_in[3], d_in[5], d_in[7], d_in[10],   // Wq, Wk, Wv, Wp
      d_in[4], d_in[6], d_in[8], d_in[11],   // bq, bk, bv, bp
      d_in[9], d_in[12], (const int*)d_in[13],
      wfrag, addb, biasf, flag);
  swin_attn_kernel<<<B, 256, 0, stream>>>(
      d_in[0], d_in[1], d_in[2], wfrag, addb, biasf, d_out, flag);
}

// Round 2
// 461.443 us; speedup vs baseline: 1.8452x; 1.1276x over previous
//
#include <hip/hip_runtime.h>
#include <hip/hip_bf16.h>

#define DIMC 128
#define HD   32
#define NTOK 49
#define SSTR 136   // ushort stride, region A (sQ/P/X') and sK/staging: 272 B rows
#define PSTR 72    // ushort stride, per-wave P scratch tiles
#define VTSTR 52   // ushort stride, sVt (V^T): 104 B rows (cols >= 52 never stored)

// LDS layout (bytes):
//  region A @0      : sQ [49][136] = 13328; later per-wave P tiles (4 x 2304 = 9216);
//                     later X' [49][136] (PV output, rows >= 49 skipped)
//  region B @13328  : sK [49][136] = 13328; later bf16 output staging [49][136]
//  region C @26656  : sVt [128][52] = 13312 (+32 pad, zero-inited: vb row-127 overread)
#define OFF_K      13328
#define OFF_VT     26656
#define SMEM_BYTES 40000   // * 4 = 160000 <= 163840 -> 4 blocks/CU (16 waves)

// workspace layout (bytes). total ~4.13 MB
#define WS_WFRAG   1024                     // ushort[4 mats][8 ntile][4 k][64 lane][8] = 131072 B
#define WS_ADDB    (1024 + 131072)          // float [64 wi][4 h][16 rtct][64 lane][4 r] = 4194304 B
#define WS_BIAS    (1024 + 131072 + 4194304) // float[4][128] = 2048 B

using bf16x8 = __attribute__((ext_vector_type(8))) __bf16;
using u16x8  = __attribute__((ext_vector_type(8))) ushort;
using f32x4  = __attribute__((ext_vector_type(4))) float;

static __device__ __forceinline__ ushort f2b(float f) {
  __hip_bfloat16 h = __float2bfloat16(f);
  return __builtin_bit_cast(ushort, h);
}
static __device__ __forceinline__ float b2f(ushort u) {
  __hip_bfloat16 h = __builtin_bit_cast(__hip_bfloat16, u);
  return __bfloat162float(h);
}
// NaN-scrubbing clamp
static __device__ __forceinline__ float scrub(float v, float lim) {
  return fminf(fmaxf(v, -lim), lim);
}
static __device__ __forceinline__ float ldany(const void* p, int i, int isbf) {
  return isbf ? b2f(((const ushort*)p)[i]) : ((const float*)p)[i];
}

// Detect whether "float" inputs were delivered as bf16 (ushort) or fp32.
__global__ void detect_dtype_kernel(const ushort* __restrict__ q, int* __restrict__ flag) {
  if (threadIdx.x == 0 && blockIdx.x == 0) {
    int c = 0;
    for (int i = 0; i < 256; ++i) {
      int e = (q[i] >> 7) & 0xFF;
      c += (e >= 110 && e <= 133) ? 1 : 0;
    }
    *flag = (c >= 200) ? 1 : 0;
  }
}

// One-time prep: weights -> bf16 fragment-major; biases -> f32; (rel_bias + mask) -> f32
// table in exact MFMA C/D accumulator layout.
__global__ __launch_bounds__(256) void prep_kernel(
    const void* __restrict__ Wq, const void* __restrict__ Wk,
    const void* __restrict__ Wv, const void* __restrict__ Wp,
    const void* __restrict__ bq, const void* __restrict__ bk,
    const void* __restrict__ bv, const void* __restrict__ bp,
    const void* __restrict__ btab, const void* __restrict__ gmask,
    const int* __restrict__ relidx,
    ushort* __restrict__ wfrag, float* __restrict__ addb, float* __restrict__ biasf,
    const int* __restrict__ flag)
{
  const int isbf = *flag;
  const int gtid = blockIdx.x * 256 + threadIdx.x;
  const int gstr = gridDim.x * 256;
  const void* Ws[4] = {Wq, Wk, Wv, Wp};
  const void* bs[4] = {bq, bk, bv, bp};

  // weight fragments: element (mat, nt, k, lane, j) = W[mat][nt*16+(lane&15)][k*32+(lane>>4)*8+j]
  for (int i = gtid; i < 4 * 16384; i += gstr) {
    int mat = i >> 14;
    int nt  = (i >> 11) & 7;
    int k   = (i >> 9) & 3;
    int ln  = (i >> 3) & 63;
    int j   = i & 7;
    int row = nt * 16 + (ln & 15);
    int col = k * 32 + (ln >> 4) * 8 + j;
    wfrag[i] = f2b(ldany(Ws[mat], row * DIMC + col, isbf));
  }
  for (int i = gtid; i < 512; i += gstr)
    biasf[i] = ldany(bs[i >> 7], i & 127, isbf);

  // addb: i = (((wi*4+h)*16 + rt*4+ct)*64 + lane)*4 + r
  for (int i = gtid; i < 64 * 4 * 16 * 64 * 4; i += gstr) {
    int r  = i & 3;
    int ln = (i >> 2) & 63;
    int rc = (i >> 8) & 15;
    int h  = (i >> 12) & 3;
    int wi = i >> 14;
    int rt = rc >> 2, ct = rc & 3;
    int n = rt * 16 + (ln >> 4) * 4 + r;
    int m = ct * 16 + (ln & 15);
    float v;
    if (n >= NTOK || m >= NTOK) {
      v = -30000.f;  // scores there are exactly 0 (zero-masked Q/K fragments), so masked hard
    } else {
      int ri = relidx[n * NTOK + m];
      v = ldany(btab, ri * 4 + h, isbf) + ldany(gmask, (wi * NTOK + n) * NTOK + m, isbf);
    }
    addb[i] = v;
  }
}

__global__ __launch_bounds__(256, 4) void swin_attn_kernel(
    const void* __restrict__ gq, const void* __restrict__ gk, const void* __restrict__ gv,
    const ushort* __restrict__ wfrag, const float* __restrict__ addb,
    const float* __restrict__ biasf,
    void* __restrict__ goutv, const int* __restrict__ flag)
{
  __shared__ __align__(16) char smem[SMEM_BYTES];
  ushort* sQ  = (ushort*)smem;
  ushort* sK  = (ushort*)(smem + OFF_K);
  ushort* sVt = (ushort*)(smem + OFF_VT);

  const int b    = blockIdx.x;
  const int tid  = threadIdx.x;
  const int wave = tid >> 6;
  const int lane = tid & 63;
  const int quad = lane >> 4;
  const int l16  = lane & 15;
  const int wi   = b & 63;
  const int isbf = *flag;
  const int h    = wave, koff = h * HD;
  const int n0a  = wave * 32, n0b = n0a + 16;

  // zero the 32 pad bytes at the end of sVt (reachable by vb's row-127 overread;
  // uninitialized LDS could hold NaN-pattern bf16 and 0*NaN = NaN in MFMA).
  if (tid < 2) ((int4*)(smem + OFF_VT + 13312))[tid] = make_int4(0, 0, 0, 0);

  // A-fragment of X loaded straight from global (rows >= NTOK -> 0)
  auto ldxfrag = [&](const void* src, int row, int col) -> bf16x8 {
    u16x8 u = {0, 0, 0, 0, 0, 0, 0, 0};
    if (row < NTOK) {
      if (isbf) {
        const ushort* s = (const ushort*)src + (size_t)b * NTOK * DIMC + row * DIMC + col;
        u = *(const u16x8*)s;
      } else {
        const float* s = (const float*)src + (size_t)b * NTOK * DIMC + row * DIMC + col;
        float4 f0 = *(const float4*)s;
        float4 f1 = *(const float4*)(s + 4);
        u[0] = f2b(f0.x); u[1] = f2b(f0.y); u[2] = f2b(f0.z); u[3] = f2b(f0.w);
        u[4] = f2b(f1.x); u[5] = f2b(f1.y); u[6] = f2b(f1.z); u[7] = f2b(f1.w);
      }
    }
    return __builtin_bit_cast(bf16x8, u);
  };

  // Projection: out[t][i] = sum_c X[t][c] * W[i][c] + bias[i]
  // wave `w` computes output features n0a..n0a+31 (= its own head's slice).
  // p: 0 -> sQ [token][feat] rows<49, 1 -> sK same, 2 -> sVt [feat][token] cols<52
  auto proj = [&](const void* src, int mat, int p) {
    const ushort* wb = wfrag + mat * 16384;
    bf16x8 bfr[2][4];
#pragma unroll
    for (int k = 0; k < 4; ++k) {
      bfr[0][k] = *(const bf16x8*)&wb[(((n0a >> 4) * 4) + k) * 512 + lane * 8];
      bfr[1][k] = *(const bf16x8*)&wb[(((n0b >> 4) * 4) + k) * 512 + lane * 8];
    }
    const float b0 = biasf[mat * 128 + n0a + l16];
    const float b1 = biasf[mat * 128 + n0b + l16];
#pragma unroll
    for (int mt = 0; mt < 4; ++mt) {
      bf16x8 af[4];
#pragma unroll
      for (int k = 0; k < 4; ++k)
        af[k] = ldxfrag(src, mt * 16 + l16, k * 32 + quad * 8);
      f32x4 a0 = {0.f, 0.f, 0.f, 0.f}, a1 = {0.f, 0.f, 0.f, 0.f};
#pragma unroll
      for (int k = 0; k < 4; ++k) {
        a0 = __builtin_amdgcn_mfma_f32_16x16x32_bf16(af[k], bfr[0][k], a0, 0, 0, 0);
        a1 = __builtin_amdgcn_mfma_f32_16x16x32_bf16(af[k], bfr[1][k], a1, 0, 0, 0);
      }
      if (p == 2) {
        // V^T: row = feature, col = token; cols >= 52 never stored (P=0 there)
        if (mt < 3 || quad == 0) {
          ushort4 pk;
          pk.x = f2b(scrub(a0[0] + b0, 30000.f)); pk.y = f2b(scrub(a0[1] + b0, 30000.f));
          pk.z = f2b(scrub(a0[2] + b0, 30000.f)); pk.w = f2b(scrub(a0[3] + b0, 30000.f));
          *(ushort4*)&sVt[(n0a + l16) * VTSTR + mt * 16 + quad * 4] = pk;
          pk.x = f2b(scrub(a1[0] + b1, 30000.f)); pk.y = f2b(scrub(a1[1] + b1, 30000.f));
          pk.z = f2b(scrub(a1[2] + b1, 30000.f)); pk.w = f2b(scrub(a1[3] + b1, 30000.f));
          *(ushort4*)&sVt[(n0b + l16) * VTSTR + mt * 16 + quad * 4] = pk;
        }
      } else {
        ushort* dst = p ? sK : sQ;
#pragma unroll
        for (int r = 0; r < 4; ++r) {
          int row = mt * 16 + quad * 4 + r;
          if (row < NTOK) {  // rows >= 49 not stored; reads are register-zero-masked
            dst[row * SSTR + n0a + l16] = f2b(scrub(a0[r] + b0, 30000.f));
            dst[row * SSTR + n0b + l16] = f2b(scrub(a1[r] + b1, 30000.f));
          }
        }
      }
    }
  };

  // ---- QKV projections (all LDS writes/reads here are wave-private: no barriers) ----
  proj(gq, 0, 0);
  proj(gk, 1, 1);
  proj(gv, 2, 2);

  // ---- scores operands: wave h owns head h; reads its own columns ----
  bf16x8 qa[4], kb[4];
#pragma unroll
  for (int t = 0; t < 4; ++t) {
    qa[t] = *(const bf16x8*)&sQ[(t * 16 + l16) * SSTR + koff + quad * 8];
    kb[t] = *(const bf16x8*)&sK[(t * 16 + l16) * SSTR + koff + quad * 8];
  }
  {
    // t=3 covers token rows 48..63: only row 48 (l16==0) is real; zero the rest.
    const u16x8 z8 = {0, 0, 0, 0, 0, 0, 0, 0};
    if (l16 != 0) {
      qa[3] = __builtin_bit_cast(bf16x8, z8);
      kb[3] = __builtin_bit_cast(bf16x8, z8);
    }
  }
  __syncthreads();  // B1: everyone holds qa/kb before P scratch clobbers region A

  // ---- per-rt: scores MFMA + (rel_bias+mask) + register softmax + P round-trip ----
  // Processing one rt tile at a time keeps accumulator pressure at 16 regs.
  const float scale = 0.17677669529663687f;  // 1/sqrt(32)
  const float* ab = addb + (size_t)(wi * 4 + h) * 16 * 256 + lane * 4;
  ushort* sP = sQ + wave * 1152;  // per-wave [16][72] scratch, 2304 B, 4 waves = 9216 B
  bf16x8 pa[4][2];
#pragma unroll
  for (int rt = 0; rt < 4; ++rt) {
    f32x4 srow[4];
#pragma unroll
    for (int ct = 0; ct < 4; ++ct) {
      f32x4 z = {0.f, 0.f, 0.f, 0.f};
      srow[ct] = __builtin_amdgcn_mfma_f32_16x16x32_bf16(qa[rt], kb[ct], z, 0, 0, 0);
    }
#pragma unroll
    for (int ct = 0; ct < 4; ++ct) {
      f32x4 a4 = *(const f32x4*)(ab + (rt * 4 + ct) * 256);
#pragma unroll
      for (int r = 0; r < 4; ++r)
        srow[ct][r] = scrub(srow[ct][r] * scale + a4[r], 30000.f);
    }
#pragma unroll
    for (int r = 0; r < 4; ++r) {
      float m0 = fmaxf(fmaxf(srow[0][r], srow[1][r]), fmaxf(srow[2][r], srow[3][r]));
      m0 = fmaxf(m0, __shfl_xor(m0, 1));
      m0 = fmaxf(m0, __shfl_xor(m0, 2));
      m0 = fmaxf(m0, __shfl_xor(m0, 4));
      m0 = fmaxf(m0, __shfl_xor(m0, 8));
      float t0 = 0.f;
#pragma unroll
      for (int ct = 0; ct < 4; ++ct) {
        float e = __expf(srow[ct][r] - m0);
        srow[ct][r] = e;
        t0 += e;
      }
      t0 += __shfl_xor(t0, 1);
      t0 += __shfl_xor(t0, 2);
      t0 += __shfl_xor(t0, 4);
      t0 += __shfl_xor(t0, 8);
      float inv = 1.0f / fmaxf(t0, 1e-20f);
#pragma unroll
      for (int ct = 0; ct < 4; ++ct) srow[ct][r] *= inv;
    }
    // P layout round-trip through wave-private scratch (in-wave DS ordering)
#pragma unroll
    for (int ct = 0; ct < 4; ++ct)
#pragma unroll
      for (int r = 0; r < 4; ++r)
        sP[(quad * 4 + r) * PSTR + ct * 16 + l16] = f2b(srow[ct][r]);
#pragma unroll
    for (int ks = 0; ks < 2; ++ks)
      pa[rt][ks] = *(const bf16x8*)&sP[l16 * PSTR + ks * 32 + quad * 8];
  }

  // ---- PV: vb reads own wave's Vt rows (wave-private); 2x 8B loads (104 B stride) ----
  auto ldvt = [&](int rowf, int colt) -> bf16x8 {
    const ushort* p = &sVt[rowf * VTSTR + colt];
    ushort4 lo = *(const ushort4*)p;
    ushort4 hi = *(const ushort4*)(p + 4);
    u16x8 u = {lo.x, lo.y, lo.z, lo.w, hi.x, hi.y, hi.z, hi.w};
    return __builtin_bit_cast(bf16x8, u);
  };
  bf16x8 vb[2][2];
#pragma unroll
  for (int ct = 0; ct < 2; ++ct)
#pragma unroll
    for (int ks = 0; ks < 2; ++ks)
      vb[ct][ks] = ldvt(koff + ct * 16 + l16, ks * 32 + quad * 8);
  f32x4 xacc[4][2];
#pragma unroll
  for (int rt = 0; rt < 4; ++rt)
#pragma unroll
    for (int ct = 0; ct < 2; ++ct) {
      f32x4 z = {0.f, 0.f, 0.f, 0.f};
      z = __builtin_amdgcn_mfma_f32_16x16x32_bf16(pa[rt][0], vb[ct][0], z, 0, 0, 0);
      xacc[rt][ct] = __builtin_amdgcn_mfma_f32_16x16x32_bf16(pa[rt][1], vb[ct][1], z, 0, 0, 0);
    }

  // out-proj weight fragments: hoist loads here to overlap with X' phase
  bf16x8 wf[2][4];
  {
    const ushort* wb = wfrag + 3 * 16384;
#pragma unroll
    for (int k = 0; k < 4; ++k) {
      wf[0][k] = *(const bf16x8*)&wb[(((n0a >> 4) * 4) + k) * 512 + lane * 8];
      wf[1][k] = *(const bf16x8*)&wb[(((n0b >> 4) * 4) + k) * 512 + lane * 8];
    }
  }
  __syncthreads();  // B2: all P-scratch reads done before X' overwrites region A

  // ---- X' -> region A as [49][136] (rows >= 49 skipped; reads of them are discarded) ----
  ushort* sXp = sQ;
#pragma unroll
  for (int rt = 0; rt < 4; ++rt)
#pragma unroll
    for (int ct = 0; ct < 2; ++ct)
#pragma unroll
      for (int r = 0; r < 4; ++r) {
        int row = rt * 16 + quad * 4 + r;
        if (row < NTOK)
          sXp[row * SSTR + koff + ct * 16 + l16] = f2b(scrub(xacc[rt][ct][r], 1e4f));
      }
  __syncthreads();  // B3: out-proj reads all X' columns

  // ---- output projection ----
  {
    const float bo0 = biasf[3 * 128 + n0a + l16];
    const float bo1 = biasf[3 * 128 + n0b + l16];
    ushort* sOut = sK;  // sK dead since B1; reuse as bf16 output staging [49][136]
#pragma unroll
    for (int mt = 0; mt < 4; ++mt) {
      bf16x8 af[4];
#pragma unroll
      for (int k = 0; k < 4; ++k)
        af[k] = *(const bf16x8*)&sXp[(mt * 16 + l16) * SSTR + k * 32 + quad * 8];
      f32x4 a0 = {0.f, 0.f, 0.f, 0.f}, a1 = {0.f, 0.f, 0.f, 0.f};
#pragma unroll
      for (int k = 0; k < 4; ++k) {
        a0 = __builtin_amdgcn_mfma_f32_16x16x32_bf16(af[k], wf[0][k], a0, 0, 0, 0);
        a1 = __builtin_amdgcn_mfma_f32_16x16x32_bf16(af[k], wf[1][k], a1, 0, 0, 0);
      }
#pragma unroll
      for (int r = 0; r < 4; ++r) {
        int row = mt * 16 + quad * 4 + r;
        if (row < NTOK) {
          float v0 = scrub(a0[r] + bo0, 1e4f);
          float v1 = scrub(a1[r] + bo1, 1e4f);
          if (isbf) {
            // stage in LDS; cooperative full-line stores below (fixes 2x write inflation)
            sOut[row * SSTR + n0a + l16] = f2b(v0);
            sOut[row * SSTR + n0b + l16] = f2b(v1);
          } else {
            size_t o = (size_t)(b * NTOK + row) * DIMC;
            ((float*)goutv)[o + n0a + l16] = v0;
            ((float*)goutv)[o + n0b + l16] = v1;
          }
        }
      }
    }
    if (isbf) {  // uniform branch across the block
      __syncthreads();  // B4: staging complete before cooperative store
      ushort* gout = (ushort*)goutv + (size_t)b * NTOK * DIMC;
      for (int c = tid; c < NTOK * 16; c += 256) {
        int row = c >> 4, j = c & 15;
        *(int4*)&gout[row * DIMC + j * 8] = *(const int4*)&sOut[row * SSTR + j * 8];
      }
    }
  }
}

extern "C" void kernel_launch(void* const* d_in, const int* in_sizes, int n_in,
                              void* d_out, int out_size, void* d_ws, size_t ws_size,
                              hipStream_t stream) {
  const int B = in_sizes[0] / (NTOK * DIMC);  // 4096
  int* flag = (int*)d_ws;
  ushort* wfrag = (ushort*)((char*)d_ws + WS_WFRAG);
  float* addb = (float*)((char*)d_ws + WS_ADDB);
  float* biasf = (float*)((char*)d_ws + WS_BIAS);
  detect_dtype_kernel<<<1, 64, 0, stream>>>((const ushort*)d_in[0], flag);
  prep_kernel<<<512, 256, 0, stream>>>(
      d_in[3], d_in[5], d_in[7], d_in[10],   // Wq, Wk, Wv, Wp
      d_in[4], d_in[6], d_in[8], d_in[11],   // bq, bk, bv, bp
      d_in[9], d_in[12], (const int*)d_in[13],
      wfrag, addb, biasf, flag);
  swin_attn_kernel<<<B, 256, 0, stream>>>(
      d_in[0], d_in[1], d_in[2], wfrag, addb, biasf, d_out, flag);
}